// Round 18
// baseline (165.312 us; speedup 1.0000x reference)
//
#include <hip/hip_runtime.h>

// DownSampler fused: x[16,3,512,512] -> out[16,3,128,128] (C folded into N: 48 imgs)
//  S1: reflect-pad1 + 4x4/s2 conv (1->20) + relu   (MFMA 32x32x16 f16)
//  S2: reflect-pad1 + 4x4/s2 conv (20->20) + relu  (MFMA 32x32x16 f16)
//  S3: 3x3 zero-pad1 conv (20->1) + relu           (VALU dot2 f16)
//
// Round 27 = round 26 + chain-depth halving (4-acc stage B, 6-chain stage C).
//  R26 CONFIRMED critical-path theory: merged halves 110->90us with
//  occupancy DROPPING 47->27%. Remaining path ~29k cyc/block vs ~5k issued.
//  This round shortens the two longest dependent chains:
//   - stage B: 2x20-deep MFMA -> 4x10-deep (a0a/a0b/a1a/a1b; per-MFMA stall
//     ~L/2 -> ~L/4). bwr hoist REMOVED (80 regs + 64 acc > 170-reg cap at
//     (256,3) would spill; in-loop w2f loads are L1-resident). Doubles as
//     the hoist-attribution test: dur>95 => hoist was R26's winner, revert.
//   - stage C: 3x40 dot2 chains -> 6x20 (di x channel-parity, static idx).
//  f32 partial-sum reorder: within absmax tolerance (already passing 0.0156).
//  Tripwire: WRITE_SIZE >> 3.1MB = spill -> re-hoist/re-balance regs.

#define NC 20
#define TS 12      // output tile
#define S1RP 600   // s_o1 dwords per rowpair block (20 cin x 30)
#define S1CIN 30   // s_o1 dwords per (rp, cin) segment
#define SO2 14     // s_o2 row stride (shorts) == row length (unpadded!)
#define PS2 196    // s_o2 channel plane stride (shorts)
#define NWG (48 * 121)
#define CPX (NWG / 8)   // 726 blocks per XCD slice

// d_ws layout (u32):
//   [0,256)       w1f[lane][4]   f16 MFMA B-frags: B[k=(l>>5)*8+j][ch=l&31] = w1[ch][k]
//   [256,5376)    w2f[cin][lane][4]  f16 B-frags, k-order per dword jp:
//                 k0 = (l>>5)*8 + (jp&1)*4 + (jp>>1)*2   (matches A interleave)
//   [5376,5556)   w3p[c][di][which]  f16 pairs; 0=(w0,w1) 1=(w2,0) 2=(0,w2)
#define W2F_OFF 256
#define W3_OFF  5376
#define WP_N    5556

typedef _Float16 h2  __attribute__((ext_vector_type(2)));
typedef __fp16   hq2 __attribute__((ext_vector_type(2)));   // cvt_pkrtz ret type
typedef _Float16 h8  __attribute__((ext_vector_type(8)));
typedef float    f32x16 __attribute__((ext_vector_type(16)));

__device__ __forceinline__ float dot2(unsigned int a, unsigned int b, float c) {
    return __builtin_amdgcn_fdot2(__builtin_bit_cast(h2, a),
                                  __builtin_bit_cast(h2, b), c, false);
}
__device__ __forceinline__ unsigned int packh(float a, float b) {
    _Float16 ha = (_Float16)a, hb = (_Float16)b;
    return (unsigned int)__builtin_bit_cast(unsigned short, ha) |
           ((unsigned int)__builtin_bit_cast(unsigned short, hb) << 16);
}
__device__ __forceinline__ unsigned int pkrtz(float a, float b) {
    hq2 r = __builtin_amdgcn_cvt_pkrtz(a, b);
    return __builtin_bit_cast(unsigned int, r);
}
__device__ __forceinline__ unsigned int pk_relu(unsigned int u) {
    unsigned int r;
    asm("v_pk_max_f16 %0, %1, 0" : "=v"(r) : "v"(u));
    return r;
}
__device__ __forceinline__ int refl256(int q) {          // reflect into [0,256)
    q = (q < 0) ? -q : q; return (q > 255) ? 510 - q : q;
}
__device__ __forceinline__ int refl512(int q) {          // reflect into [0,512)
    q = (q < 0) ? -q : q; return (q > 511) ? 1022 - q : q;
}

__global__ __launch_bounds__(256) void pack_weights(
    const float* __restrict__ w1, const float* __restrict__ w2,
    const float* __restrict__ w3, unsigned int* __restrict__ wp)
{
    const int i = blockIdx.x * 256 + threadIdx.x;
    if (i >= WP_N) return;
    if (i < W2F_OFF) {                      // w1f (stage-A GEMM: unchanged)
        const int lane = i >> 2, jp = i & 3;
        const int ch = lane & 31, k0 = (lane >> 5) * 8 + 2 * jp;
        wp[i] = (ch < NC) ? packh(w1[ch * 16 + k0], w1[ch * 16 + k0 + 1]) : 0u;
    } else if (i < W3_OFF) {                // w2f (k-permuted to match A reads)
        const int t = i - W2F_OFF;
        const int cin = t >> 8, r = t & 255;
        const int lane = r >> 2, jp = r & 3;
        const int cout = lane & 31;
        const int k0 = (lane >> 5) * 8 + ((jp & 1) << 2) + ((jp >> 1) << 1);
        wp[i] = (cout < NC) ? packh(w2[(cout * NC + cin) * 16 + k0],
                                    w2[(cout * NC + cin) * 16 + k0 + 1]) : 0u;
    } else {                                // w3p
        const int t = i - W3_OFF;
        const int c = t / 9;
        const int r = t - c * 9;
        const int di = r / 3, wh = r - di * 3;
        const float* row = w3 + c * 9 + di * 3;
        float a, b;
        if (wh == 0)      { a = row[0]; b = row[1]; }
        else if (wh == 1) { a = row[2]; b = 0.f;    }
        else              { a = 0.f;    b = row[2]; }
        wp[i] = packh(a, b);
    }
}

// Load + pack one half's x-taps for this thread's 4 stage-A chunks.
__device__ __forceinline__ void load_taps(
    const float* __restrict__ xi, int t0, int h, int wv, int kh,
    bool rowEdge, bool colEdge, int vb, int v0, int v1, int v2, int v3,
    unsigned int xw[4][4])
{
    #pragma unroll
    for (int i = 0; i < 4; ++i) {
        const int c = wv + 4 * i;
        const int t = t0 + 14 * h + c;     // o1pad row (garbage-safe OOR)
        int rlo, rhi;
        if (!rowEdge) {
            rlo = 2 * t - 3 + 2 * kh;      // interior-proven in range
            rhi = rlo + 1;
        } else {
            const int mr = refl256(t - 1);
            const int rb = 2 * mr - 1 + 2 * kh;
            rlo = refl512(rb);
            rhi = refl512(rb + 1);
        }
        const float* __restrict__ plo = xi + rlo * 512;
        const float* __restrict__ phi = xi + rhi * 512;
        float f0, f1, f2, f3, f4, f5, f6, f7;
        if (!colEdge) {
            f0 = plo[vb]; f1 = plo[vb + 1]; f2 = plo[vb + 2]; f3 = plo[vb + 3];
            f4 = phi[vb]; f5 = phi[vb + 1]; f6 = phi[vb + 2]; f7 = phi[vb + 3];
        } else {
            f0 = plo[v0]; f1 = plo[v1]; f2 = plo[v2]; f3 = plo[v3];
            f4 = phi[v0]; f5 = phi[v1]; f6 = phi[v2]; f7 = phi[v3];
        }
        xw[i][0] = pkrtz(f0, f1); xw[i][1] = pkrtz(f2, f3);
        xw[i][2] = pkrtz(f4, f5); xw[i][3] = pkrtz(f6, f7);
    }
}

__global__ __launch_bounds__(256, 3) void ds_fused(
    const float* __restrict__ x,              // [48][512][512]
    const unsigned int* __restrict__ wp,      // packed weights (d_ws)
    float* __restrict__ out)                  // [48][128][128]
{
    __shared__ __attribute__((aligned(16))) unsigned short s_o1[15 * S1RP * 2]; // 36,000 B
    __shared__ __attribute__((aligned(16))) unsigned short s_o2[NC * PS2];      //  7,840 B

    // XCD-aware bijective swizzle: consecutive hardware ids round-robin XCDs;
    // give each XCD a contiguous slice of 726 blocks (= exactly 6 images).
    const int rawb = blockIdx.x;
    const int bid  = (rawb & 7) * CPX + (rawb >> 3);

    const int img  = bid / 121;
    const int t121 = bid - img * 121;
    const int ty   = t121 / 11;
    const int tx   = t121 - ty * 11;
    const int y0   = ty * TS;
    const int x0   = tx * TS;
    const int tid  = threadIdx.x;
    const int lane = tid & 63;
    const int wv   = tid >> 6;
    const int l31  = lane & 31;
    const int kh   = lane >> 5;

    const float* __restrict__ xi = x + (size_t)img * (512 * 512);
    const uint4* __restrict__ w1f = (const uint4*)wp;
    const uint4* __restrict__ w2f = (const uint4*)(wp + W2F_OFF);
    const unsigned int* __restrict__ w3p = wp + W3_OFF;

    const int t0 = 2 * y0 - 2;            // o1pad row base of tile
    const int s0 = 2 * x0 - 2;            // o1pad col base

    // ---- stage-A per-lane column data (chunk covers cols b = l31) ----
    const int sA = s0 + l31;              // o1pad col (garbage-safe overflow)
    const bool rowEdge = (ty == 0) || (ty == 10);
    const bool colEdge = (tx == 0) || (tx == 10);
    const bool interior = !rowEdge && !colEdge;
    const int vb = 2 * sA - 3;            // interior fast path taps vb..vb+3
    int v0 = 0, v1 = 0, v2 = 0, v3 = 0;
    if (colEdge) {
        const int n2 = refl256(sA - 1);
        const int vbb = 2 * n2 - 1;
        v0 = refl512(vbb);     v1 = refl512(vbb + 1);
        v2 = refl512(vbb + 2); v3 = refl512(vbb + 3);
    }
    const h8 w1frag = __builtin_bit_cast(h8, w1f[lane]);

    // ---- stage-B per-lane position (chunk = wv), h-independent ----
    const int q  = 32 * wv + l31;         // 0..127; valid < 98 (7x14 per half)
    const int qc = (q < 98) ? q : 0;      // clamp invalid lanes to a safe addr
    const int li = (qc * 2341) >> 15;     // /14 for q<128
    const int jl = qc - li * 14;
    const int offR0 = (li + kh) * (S1RP / 2) + jl;      // h=0 rowpairs 0..7
    const int offR1 = offR0 + 7 * (S1RP / 2);           // h=1 rowpairs 7..14

    unsigned int* const s1d = (unsigned int*)s_o1;
    const uint2* const so1v = (const uint2*)s_o1;

    // ---- load ALL taps (both halves) in one MLP window ----
    unsigned int xw0[4][4], xw1[4][4];
    load_taps(xi, t0, 0, wv, kh, rowEdge, colEdge, vb, v0, v1, v2, v3, xw0);
    load_taps(xi, t0, 1, wv, kh, rowEdge, colEdge, vb, v0, v1, v2, v3, xw1);

    // ---- stage A: both halves -> s_o1 (15 rowpairs), then ONE barrier ----
    #pragma unroll
    for (int i = 0; i < 4; ++i) {
        const int c = wv + 4 * i;
        uint4 aw; aw.x = xw0[i][0]; aw.y = xw0[i][1];
                  aw.z = xw0[i][2]; aw.w = xw0[i][3];
        f32x16 o = {};
        o = __builtin_amdgcn_mfma_f32_32x32x16_f16(
                __builtin_bit_cast(h8, aw), w1frag, o, 0, 0, 0);
        if (l31 < NC) {
            unsigned int* wr = s1d + (c >> 1) * S1RP + l31 * S1CIN + (c & 1);
            const int kb = 4 * kh;        // col-dwords j = 2kh + {0,1,4,5,...}
            wr[kb + 0]  = pk_relu(pkrtz(o[0],  o[1]));
            wr[kb + 2]  = pk_relu(pkrtz(o[2],  o[3]));
            wr[kb + 8]  = pk_relu(pkrtz(o[4],  o[5]));
            wr[kb + 10] = pk_relu(pkrtz(o[6],  o[7]));
            wr[kb + 16] = pk_relu(pkrtz(o[8],  o[9]));
            wr[kb + 18] = pk_relu(pkrtz(o[10], o[11]));
            wr[kb + 24] = pk_relu(pkrtz(o[12], o[13]));
            if (kh == 0)  // j=15 (cols 30,31) never read: suppressed
                wr[kb + 26] = pk_relu(pkrtz(o[14], o[15]));
        }
    }
    #pragma unroll
    for (int i = 0; i < 4; ++i) {
        const int c = wv + 4 * i;         // h1 row = 14 + c -> rowpair 7+(c>>1)
        uint4 aw; aw.x = xw1[i][0]; aw.y = xw1[i][1];
                  aw.z = xw1[i][2]; aw.w = xw1[i][3];
        f32x16 o = {};
        o = __builtin_amdgcn_mfma_f32_32x32x16_f16(
                __builtin_bit_cast(h8, aw), w1frag, o, 0, 0, 0);
        // c<2 duplicates h0's rows 14,15 (identical values): skip to avoid
        // a same-address write race.
        if (l31 < NC && c >= 2) {
            unsigned int* wr =
                s1d + (7 + (c >> 1)) * S1RP + l31 * S1CIN + (c & 1);
            const int kb = 4 * kh;
            wr[kb + 0]  = pk_relu(pkrtz(o[0],  o[1]));
            wr[kb + 2]  = pk_relu(pkrtz(o[2],  o[3]));
            wr[kb + 8]  = pk_relu(pkrtz(o[4],  o[5]));
            wr[kb + 10] = pk_relu(pkrtz(o[6],  o[7]));
            wr[kb + 16] = pk_relu(pkrtz(o[8],  o[9]));
            wr[kb + 18] = pk_relu(pkrtz(o[10], o[11]));
            wr[kb + 24] = pk_relu(pkrtz(o[12], o[13]));
            if (kh == 0)
                wr[kb + 26] = pk_relu(pkrtz(o[14], o[15]));
        }
    }
    __syncthreads();                      // barrier 1: all s_o1 visible

    // ---- stage B: FOUR independent 10-MFMA chains (in-loop L1 weights) ----
    f32x16 a0a = {}, a0b = {}, a1a = {}, a1b = {};
    #pragma unroll
    for (int cin = 0; cin < NC; cin += 2) {
        const uint4 bw0 = w2f[cin * 64 + lane];
        const uint4 bw1 = w2f[(cin + 1) * 64 + lane];
        const uint2* pA0 = so1v + cin * (S1CIN / 2) + offR0;
        const uint2* pA1 = so1v + cin * (S1CIN / 2) + offR1;
        const uint2* pB0 = so1v + (cin + 1) * (S1CIN / 2) + offR0;
        const uint2* pB1 = so1v + (cin + 1) * (S1CIN / 2) + offR1;
        const uint2 lo0 = pA0[0], hi0 = pA0[1];
        const uint2 lo1 = pA1[0], hi1 = pA1[1];
        const uint2 lo2 = pB0[0], hi2 = pB0[1];
        const uint2 lo3 = pB1[0], hi3 = pB1[1];
        uint4 aw0; aw0.x = lo0.x; aw0.y = lo0.y; aw0.z = hi0.x; aw0.w = hi0.y;
        uint4 aw1; aw1.x = lo1.x; aw1.y = lo1.y; aw1.z = hi1.x; aw1.w = hi1.y;
        uint4 aw2; aw2.x = lo2.x; aw2.y = lo2.y; aw2.z = hi2.x; aw2.w = hi2.y;
        uint4 aw3; aw3.x = lo3.x; aw3.y = lo3.y; aw3.z = hi3.x; aw3.w = hi3.y;
        a0a = __builtin_amdgcn_mfma_f32_32x32x16_f16(
                  __builtin_bit_cast(h8, aw0),
                  __builtin_bit_cast(h8, bw0), a0a, 0, 0, 0);
        a1a = __builtin_amdgcn_mfma_f32_32x32x16_f16(
                  __builtin_bit_cast(h8, aw1),
                  __builtin_bit_cast(h8, bw0), a1a, 0, 0, 0);
        a0b = __builtin_amdgcn_mfma_f32_32x32x16_f16(
                  __builtin_bit_cast(h8, aw2),
                  __builtin_bit_cast(h8, bw1), a0b, 0, 0, 0);
        a1b = __builtin_amdgcn_mfma_f32_32x32x16_f16(
                  __builtin_bit_cast(h8, aw3),
                  __builtin_bit_cast(h8, bw1), a1b, 0, 0, 0);
    }
    const f32x16 acc0 = a0a + a0b;
    const f32x16 acc1 = a1a + a1b;

    // ---- epilogues: acc0 -> s_o2 half 0, acc1 -> half 1 ----
    if (l31 < NC) {
        #pragma unroll
        for (int h = 0; h < 2; ++h) {
            const f32x16& acc = h ? acc1 : acc0;
            unsigned short* bp = &s_o2[l31 * PS2 + 98 * h + 32 * wv + 4 * kh];
            if (interior) {
                #pragma unroll
                for (int j = 0; j < 4; ++j) {
                    const int Q = 32 * wv + 4 * kh + 8 * j;
                    if (Q < 98)
                        *(unsigned int*)(bp + 8 * j) =
                            pk_relu(pkrtz(acc[4 * j], acc[4 * j + 1]));
                    if (Q + 2 < 98)
                        *(unsigned int*)(bp + 8 * j + 2) =
                            pk_relu(pkrtz(acc[4 * j + 2], acc[4 * j + 3]));
                }
            } else {
                #pragma unroll
                for (int d = 0; d < 8; ++d) {
                    const int jj = d >> 1, ss = d & 1;
                    const int Qd = 32 * wv + 4 * kh + 8 * jj + 2 * ss;
                    if (Qd < 98) {
                        const int li2 = (Qd * 2341) >> 15;
                        const int jl2 = Qd - li2 * 14;
                        const int oi  = y0 - 1 + 7 * h + li2;
                        const int oj  = x0 - 1 + jl2;
                        const bool rok = (oi >= 0) && (oi < 128);
                        const unsigned int m =
                            (rok && oj >= 0 && oj < 128 ? 0x0000FFFFu : 0u) |
                            (rok && oj + 1 < 128        ? 0xFFFF0000u : 0u);
                        *(unsigned int*)(bp + 8 * jj + 2 * ss) =
                            pk_relu(pkrtz(acc[4 * jj + 2 * ss],
                                          acc[4 * jj + 2 * ss + 1])) & m;
                    }
                }
            }
        }
    }
    __syncthreads();                      // barrier 2: s_o2 visible

    // ---- stage C: 3x3 conv over s_o2 -> out (6 chains: di x ch-parity) ----
    if (tid < TS * TS) {
        const int oy = tid / TS;
        const int ox = tid - oy * TS;
        const int e  = ox & ~1;
        const int par = ox & 1;
        const unsigned int shp = (unsigned int)(par << 4);  // alignbit shift
        const unsigned int* wsel = w3p + 1 + par;           // wb (par=0) / wc (par=1)
        float a0e = 0.f, a1e = 0.f, a2e = 0.f;
        float a0o = 0.f, a1o = 0.f, a2o = 0.f;
        #pragma unroll
        for (int c = 0; c < NC; ++c) {
            const unsigned short* pl = &s_o2[c * PS2 + oy * SO2 + e];
            #pragma unroll
            for (int di = 0; di < 3; ++di) {
                const unsigned int* row = (const unsigned int*)(pl + di * SO2);
                const unsigned int d0 = row[0];
                const unsigned int d1 = row[1];
                const unsigned int u0 = __builtin_amdgcn_alignbit(d1, d0, shp);
                const unsigned int wa = w3p[c * 9 + di * 3 + 0];
                const unsigned int wz = wsel[c * 9 + di * 3];
                float& aR = (c & 1)
                    ? ((di == 0) ? a0o : ((di == 1) ? a1o : a2o))
                    : ((di == 0) ? a0e : ((di == 1) ? a1e : a2e));
                aR = dot2(u0, wa, aR);
                aR = dot2(d1, wz, aR);
            }
        }
        const float accc = (a0e + a0o) + (a1e + a1o) + (a2e + a2o);
        const int gy = y0 + oy, gx = x0 + ox;
        if (gy < 128 && gx < 128)   // tiles cover 132>128 px: guard edge tiles
            out[(size_t)img * (128 * 128) + gy * 128 + gx] = fmaxf(accc, 0.f);
    }
}

extern "C" void kernel_launch(void* const* d_in, const int* in_sizes, int n_in,
                              void* d_out, int out_size, void* d_ws, size_t ws_size,
                              hipStream_t stream) {
    const float* x  = (const float*)d_in[0];
    const float* w1 = (const float*)d_in[1];
    const float* w2 = (const float*)d_in[2];
    const float* w3 = (const float*)d_in[3];
    unsigned int* wp = (unsigned int*)d_ws;
    float* out = (float*)d_out;
    pack_weights<<<dim3((WP_N + 255) / 256), dim3(256), 0, stream>>>(w1, w2, w3, wp);
    ds_fused<<<dim3(NWG), dim3(256), 0, stream>>>(x, wp, out);
}

// Round 19
// 154.899 us; speedup vs baseline: 1.0672x; 1.0672x over previous
//
#include <hip/hip_runtime.h>

// DownSampler fused: x[16,3,512,512] -> out[16,3,128,128] (C folded into N: 48 imgs)
//  S1: reflect-pad1 + 4x4/s2 conv (1->20) + relu   (MFMA 32x32x16 f16)
//  S2: reflect-pad1 + 4x4/s2 conv (20->20) + relu  (MFMA 32x32x16 f16)
//  S3: 3x3 zero-pad1 conv (20->1) + relu           (VALU dot2 f16)
//
// Round 28 = revert to R26 stage A/B + keep only R27's 6-chain stage C.
//  R27 regressed 90->104us. Attribution: in-loop w2f loads put ~200cyc L2
//  latency INSIDE the stage-B dependent region (VGPR 84->68 shows compiler
//  didn't re-hoist); ~23k cyc/CU ~ 10us, matches. Chain-depth halving was
//  worth ~3us at best -- swamped. Lesson (3rd confirmation): latency
//  placement inside/outside dependent chains is THE lever in this regime.
//  This round: R26's hoisted-bwr 2x20-chain stage B restored exactly;
//  stage C keeps the 6-chain split (independent, low-risk).
//  Attribution test: ~90 => 6-chain null, R27 fully explained by un-hoist;
//  <87 => 6-chain real; ~104 => attribution wrong (4-acc was the problem).

#define NC 20
#define TS 12      // output tile
#define S1RP 600   // s_o1 dwords per rowpair block (20 cin x 30)
#define S1CIN 30   // s_o1 dwords per (rp, cin) segment
#define SO2 14     // s_o2 row stride (shorts) == row length (unpadded!)
#define PS2 196    // s_o2 channel plane stride (shorts)
#define NWG (48 * 121)
#define CPX (NWG / 8)   // 726 blocks per XCD slice

// d_ws layout (u32):
//   [0,256)       w1f[lane][4]   f16 MFMA B-frags: B[k=(l>>5)*8+j][ch=l&31] = w1[ch][k]
//   [256,5376)    w2f[cin][lane][4]  f16 B-frags, k-order per dword jp:
//                 k0 = (l>>5)*8 + (jp&1)*4 + (jp>>1)*2   (matches A interleave)
//   [5376,5556)   w3p[c][di][which]  f16 pairs; 0=(w0,w1) 1=(w2,0) 2=(0,w2)
#define W2F_OFF 256
#define W3_OFF  5376
#define WP_N    5556

typedef _Float16 h2  __attribute__((ext_vector_type(2)));
typedef __fp16   hq2 __attribute__((ext_vector_type(2)));   // cvt_pkrtz ret type
typedef _Float16 h8  __attribute__((ext_vector_type(8)));
typedef float    f32x16 __attribute__((ext_vector_type(16)));

__device__ __forceinline__ float dot2(unsigned int a, unsigned int b, float c) {
    return __builtin_amdgcn_fdot2(__builtin_bit_cast(h2, a),
                                  __builtin_bit_cast(h2, b), c, false);
}
__device__ __forceinline__ unsigned int packh(float a, float b) {
    _Float16 ha = (_Float16)a, hb = (_Float16)b;
    return (unsigned int)__builtin_bit_cast(unsigned short, ha) |
           ((unsigned int)__builtin_bit_cast(unsigned short, hb) << 16);
}
__device__ __forceinline__ unsigned int pkrtz(float a, float b) {
    hq2 r = __builtin_amdgcn_cvt_pkrtz(a, b);
    return __builtin_bit_cast(unsigned int, r);
}
__device__ __forceinline__ unsigned int pk_relu(unsigned int u) {
    unsigned int r;
    asm("v_pk_max_f16 %0, %1, 0" : "=v"(r) : "v"(u));
    return r;
}
__device__ __forceinline__ int refl256(int q) {          // reflect into [0,256)
    q = (q < 0) ? -q : q; return (q > 255) ? 510 - q : q;
}
__device__ __forceinline__ int refl512(int q) {          // reflect into [0,512)
    q = (q < 0) ? -q : q; return (q > 511) ? 1022 - q : q;
}

__global__ __launch_bounds__(256) void pack_weights(
    const float* __restrict__ w1, const float* __restrict__ w2,
    const float* __restrict__ w3, unsigned int* __restrict__ wp)
{
    const int i = blockIdx.x * 256 + threadIdx.x;
    if (i >= WP_N) return;
    if (i < W2F_OFF) {                      // w1f (stage-A GEMM: unchanged)
        const int lane = i >> 2, jp = i & 3;
        const int ch = lane & 31, k0 = (lane >> 5) * 8 + 2 * jp;
        wp[i] = (ch < NC) ? packh(w1[ch * 16 + k0], w1[ch * 16 + k0 + 1]) : 0u;
    } else if (i < W3_OFF) {                // w2f (k-permuted to match A reads)
        const int t = i - W2F_OFF;
        const int cin = t >> 8, r = t & 255;
        const int lane = r >> 2, jp = r & 3;
        const int cout = lane & 31;
        const int k0 = (lane >> 5) * 8 + ((jp & 1) << 2) + ((jp >> 1) << 1);
        wp[i] = (cout < NC) ? packh(w2[(cout * NC + cin) * 16 + k0],
                                    w2[(cout * NC + cin) * 16 + k0 + 1]) : 0u;
    } else {                                // w3p
        const int t = i - W3_OFF;
        const int c = t / 9;
        const int r = t - c * 9;
        const int di = r / 3, wh = r - di * 3;
        const float* row = w3 + c * 9 + di * 3;
        float a, b;
        if (wh == 0)      { a = row[0]; b = row[1]; }
        else if (wh == 1) { a = row[2]; b = 0.f;    }
        else              { a = 0.f;    b = row[2]; }
        wp[i] = packh(a, b);
    }
}

// Load + pack one half's x-taps for this thread's 4 stage-A chunks.
__device__ __forceinline__ void load_taps(
    const float* __restrict__ xi, int t0, int h, int wv, int kh,
    bool rowEdge, bool colEdge, int vb, int v0, int v1, int v2, int v3,
    unsigned int xw[4][4])
{
    #pragma unroll
    for (int i = 0; i < 4; ++i) {
        const int c = wv + 4 * i;
        const int t = t0 + 14 * h + c;     // o1pad row (garbage-safe OOR)
        int rlo, rhi;
        if (!rowEdge) {
            rlo = 2 * t - 3 + 2 * kh;      // interior-proven in range
            rhi = rlo + 1;
        } else {
            const int mr = refl256(t - 1);
            const int rb = 2 * mr - 1 + 2 * kh;
            rlo = refl512(rb);
            rhi = refl512(rb + 1);
        }
        const float* __restrict__ plo = xi + rlo * 512;
        const float* __restrict__ phi = xi + rhi * 512;
        float f0, f1, f2, f3, f4, f5, f6, f7;
        if (!colEdge) {
            f0 = plo[vb]; f1 = plo[vb + 1]; f2 = plo[vb + 2]; f3 = plo[vb + 3];
            f4 = phi[vb]; f5 = phi[vb + 1]; f6 = phi[vb + 2]; f7 = phi[vb + 3];
        } else {
            f0 = plo[v0]; f1 = plo[v1]; f2 = plo[v2]; f3 = plo[v3];
            f4 = phi[v0]; f5 = phi[v1]; f6 = phi[v2]; f7 = phi[v3];
        }
        xw[i][0] = pkrtz(f0, f1); xw[i][1] = pkrtz(f2, f3);
        xw[i][2] = pkrtz(f4, f5); xw[i][3] = pkrtz(f6, f7);
    }
}

__global__ __launch_bounds__(256, 3) void ds_fused(
    const float* __restrict__ x,              // [48][512][512]
    const unsigned int* __restrict__ wp,      // packed weights (d_ws)
    float* __restrict__ out)                  // [48][128][128]
{
    __shared__ __attribute__((aligned(16))) unsigned short s_o1[15 * S1RP * 2]; // 36,000 B
    __shared__ __attribute__((aligned(16))) unsigned short s_o2[NC * PS2];      //  7,840 B

    // XCD-aware bijective swizzle: consecutive hardware ids round-robin XCDs;
    // give each XCD a contiguous slice of 726 blocks (= exactly 6 images).
    const int rawb = blockIdx.x;
    const int bid  = (rawb & 7) * CPX + (rawb >> 3);

    const int img  = bid / 121;
    const int t121 = bid - img * 121;
    const int ty   = t121 / 11;
    const int tx   = t121 - ty * 11;
    const int y0   = ty * TS;
    const int x0   = tx * TS;
    const int tid  = threadIdx.x;
    const int lane = tid & 63;
    const int wv   = tid >> 6;
    const int l31  = lane & 31;
    const int kh   = lane >> 5;

    const float* __restrict__ xi = x + (size_t)img * (512 * 512);
    const uint4* __restrict__ w1f = (const uint4*)wp;
    const uint4* __restrict__ w2f = (const uint4*)(wp + W2F_OFF);
    const unsigned int* __restrict__ w3p = wp + W3_OFF;

    const int t0 = 2 * y0 - 2;            // o1pad row base of tile
    const int s0 = 2 * x0 - 2;            // o1pad col base

    // ---- stage-A per-lane column data (chunk covers cols b = l31) ----
    const int sA = s0 + l31;              // o1pad col (garbage-safe overflow)
    const bool rowEdge = (ty == 0) || (ty == 10);
    const bool colEdge = (tx == 0) || (tx == 10);
    const bool interior = !rowEdge && !colEdge;
    const int vb = 2 * sA - 3;            // interior fast path taps vb..vb+3
    int v0 = 0, v1 = 0, v2 = 0, v3 = 0;
    if (colEdge) {
        const int n2 = refl256(sA - 1);
        const int vbb = 2 * n2 - 1;
        v0 = refl512(vbb);     v1 = refl512(vbb + 1);
        v2 = refl512(vbb + 2); v3 = refl512(vbb + 3);
    }
    const h8 w1frag = __builtin_bit_cast(h8, w1f[lane]);

    // ---- stage-B per-lane position (chunk = wv), h-independent ----
    const int q  = 32 * wv + l31;         // 0..127; valid < 98 (7x14 per half)
    const int qc = (q < 98) ? q : 0;      // clamp invalid lanes to a safe addr
    const int li = (qc * 2341) >> 15;     // /14 for q<128
    const int jl = qc - li * 14;
    const int offR0 = (li + kh) * (S1RP / 2) + jl;      // h=0 rowpairs 0..7
    const int offR1 = offR0 + 7 * (S1RP / 2);           // h=1 rowpairs 7..14

    unsigned int* const s1d = (unsigned int*)s_o1;
    const uint2* const so1v = (const uint2*)s_o1;

    // ---- load ALL taps (both halves) in one MLP window ----
    unsigned int xw0[4][4], xw1[4][4];
    load_taps(xi, t0, 0, wv, kh, rowEdge, colEdge, vb, v0, v1, v2, v3, xw0);
    load_taps(xi, t0, 1, wv, kh, rowEdge, colEdge, vb, v0, v1, v2, v3, xw1);

    // ---- hoist h-invariant stage-B weights into registers (80 VGPRs) ----
    // (R27 lesson: these loads INSIDE stage B expose ~200cyc/iter; keep them
    //  issued upfront, overlapping the tap window.)
    uint4 bwr[NC];
    #pragma unroll
    for (int cin = 0; cin < NC; ++cin) bwr[cin] = w2f[cin * 64 + lane];

    // ---- stage A: both halves -> s_o1 (15 rowpairs), then ONE barrier ----
    #pragma unroll
    for (int i = 0; i < 4; ++i) {
        const int c = wv + 4 * i;
        uint4 aw; aw.x = xw0[i][0]; aw.y = xw0[i][1];
                  aw.z = xw0[i][2]; aw.w = xw0[i][3];
        f32x16 o = {};
        o = __builtin_amdgcn_mfma_f32_32x32x16_f16(
                __builtin_bit_cast(h8, aw), w1frag, o, 0, 0, 0);
        if (l31 < NC) {
            unsigned int* wr = s1d + (c >> 1) * S1RP + l31 * S1CIN + (c & 1);
            const int kb = 4 * kh;        // col-dwords j = 2kh + {0,1,4,5,...}
            wr[kb + 0]  = pk_relu(pkrtz(o[0],  o[1]));
            wr[kb + 2]  = pk_relu(pkrtz(o[2],  o[3]));
            wr[kb + 8]  = pk_relu(pkrtz(o[4],  o[5]));
            wr[kb + 10] = pk_relu(pkrtz(o[6],  o[7]));
            wr[kb + 16] = pk_relu(pkrtz(o[8],  o[9]));
            wr[kb + 18] = pk_relu(pkrtz(o[10], o[11]));
            wr[kb + 24] = pk_relu(pkrtz(o[12], o[13]));
            if (kh == 0)  // j=15 (cols 30,31) never read: suppressed
                wr[kb + 26] = pk_relu(pkrtz(o[14], o[15]));
        }
    }
    #pragma unroll
    for (int i = 0; i < 4; ++i) {
        const int c = wv + 4 * i;         // h1 row = 14 + c -> rowpair 7+(c>>1)
        uint4 aw; aw.x = xw1[i][0]; aw.y = xw1[i][1];
                  aw.z = xw1[i][2]; aw.w = xw1[i][3];
        f32x16 o = {};
        o = __builtin_amdgcn_mfma_f32_32x32x16_f16(
                __builtin_bit_cast(h8, aw), w1frag, o, 0, 0, 0);
        // c<2 duplicates h0's rows 14,15 (identical values): skip to avoid
        // a same-address write race.
        if (l31 < NC && c >= 2) {
            unsigned int* wr =
                s1d + (7 + (c >> 1)) * S1RP + l31 * S1CIN + (c & 1);
            const int kb = 4 * kh;
            wr[kb + 0]  = pk_relu(pkrtz(o[0],  o[1]));
            wr[kb + 2]  = pk_relu(pkrtz(o[2],  o[3]));
            wr[kb + 8]  = pk_relu(pkrtz(o[4],  o[5]));
            wr[kb + 10] = pk_relu(pkrtz(o[6],  o[7]));
            wr[kb + 16] = pk_relu(pkrtz(o[8],  o[9]));
            wr[kb + 18] = pk_relu(pkrtz(o[10], o[11]));
            wr[kb + 24] = pk_relu(pkrtz(o[12], o[13]));
            if (kh == 0)
                wr[kb + 26] = pk_relu(pkrtz(o[14], o[15]));
        }
    }
    __syncthreads();                      // barrier 1: all s_o1 visible

    // ---- stage B: TWO independent 20-MFMA chains (full unroll: bwr regs) ----
    f32x16 acc0 = {}, acc1 = {};
    #pragma unroll
    for (int cin = 0; cin < NC; ++cin) {
        const uint2* pA0 = so1v + cin * (S1CIN / 2) + offR0;
        const uint2* pA1 = so1v + cin * (S1CIN / 2) + offR1;
        const uint2 lo0 = pA0[0], hi0 = pA0[1];
        const uint2 lo1 = pA1[0], hi1 = pA1[1];
        uint4 aw0; aw0.x = lo0.x; aw0.y = lo0.y; aw0.z = hi0.x; aw0.w = hi0.y;
        uint4 aw1; aw1.x = lo1.x; aw1.y = lo1.y; aw1.z = hi1.x; aw1.w = hi1.y;
        acc0 = __builtin_amdgcn_mfma_f32_32x32x16_f16(
                   __builtin_bit_cast(h8, aw0),
                   __builtin_bit_cast(h8, bwr[cin]), acc0, 0, 0, 0);
        acc1 = __builtin_amdgcn_mfma_f32_32x32x16_f16(
                   __builtin_bit_cast(h8, aw1),
                   __builtin_bit_cast(h8, bwr[cin]), acc1, 0, 0, 0);
    }

    // ---- epilogues: acc0 -> s_o2 half 0, acc1 -> half 1 ----
    if (l31 < NC) {
        #pragma unroll
        for (int h = 0; h < 2; ++h) {
            const f32x16& acc = h ? acc1 : acc0;
            unsigned short* bp = &s_o2[l31 * PS2 + 98 * h + 32 * wv + 4 * kh];
            if (interior) {
                #pragma unroll
                for (int j = 0; j < 4; ++j) {
                    const int Q = 32 * wv + 4 * kh + 8 * j;
                    if (Q < 98)
                        *(unsigned int*)(bp + 8 * j) =
                            pk_relu(pkrtz(acc[4 * j], acc[4 * j + 1]));
                    if (Q + 2 < 98)
                        *(unsigned int*)(bp + 8 * j + 2) =
                            pk_relu(pkrtz(acc[4 * j + 2], acc[4 * j + 3]));
                }
            } else {
                #pragma unroll
                for (int d = 0; d < 8; ++d) {
                    const int jj = d >> 1, ss = d & 1;
                    const int Qd = 32 * wv + 4 * kh + 8 * jj + 2 * ss;
                    if (Qd < 98) {
                        const int li2 = (Qd * 2341) >> 15;
                        const int jl2 = Qd - li2 * 14;
                        const int oi  = y0 - 1 + 7 * h + li2;
                        const int oj  = x0 - 1 + jl2;
                        const bool rok = (oi >= 0) && (oi < 128);
                        const unsigned int m =
                            (rok && oj >= 0 && oj < 128 ? 0x0000FFFFu : 0u) |
                            (rok && oj + 1 < 128        ? 0xFFFF0000u : 0u);
                        *(unsigned int*)(bp + 8 * jj + 2 * ss) =
                            pk_relu(pkrtz(acc[4 * jj + 2 * ss],
                                          acc[4 * jj + 2 * ss + 1])) & m;
                    }
                }
            }
        }
    }
    __syncthreads();                      // barrier 2: s_o2 visible

    // ---- stage C: 3x3 conv over s_o2 -> out (6 chains: di x ch-parity) ----
    if (tid < TS * TS) {
        const int oy = tid / TS;
        const int ox = tid - oy * TS;
        const int e  = ox & ~1;
        const int par = ox & 1;
        const unsigned int shp = (unsigned int)(par << 4);  // alignbit shift
        const unsigned int* wsel = w3p + 1 + par;           // wb (par=0) / wc (par=1)
        float a0e = 0.f, a1e = 0.f, a2e = 0.f;
        float a0o = 0.f, a1o = 0.f, a2o = 0.f;
        #pragma unroll
        for (int c = 0; c < NC; ++c) {
            const unsigned short* pl = &s_o2[c * PS2 + oy * SO2 + e];
            #pragma unroll
            for (int di = 0; di < 3; ++di) {
                const unsigned int* row = (const unsigned int*)(pl + di * SO2);
                const unsigned int d0 = row[0];
                const unsigned int d1 = row[1];
                const unsigned int u0 = __builtin_amdgcn_alignbit(d1, d0, shp);
                const unsigned int wa = w3p[c * 9 + di * 3 + 0];
                const unsigned int wz = wsel[c * 9 + di * 3];
                float& aR = (c & 1)
                    ? ((di == 0) ? a0o : ((di == 1) ? a1o : a2o))
                    : ((di == 0) ? a0e : ((di == 1) ? a1e : a2e));
                aR = dot2(u0, wa, aR);
                aR = dot2(d1, wz, aR);
            }
        }
        const float accc = (a0e + a0o) + (a1e + a1o) + (a2e + a2o);
        const int gy = y0 + oy, gx = x0 + ox;
        if (gy < 128 && gx < 128)   // tiles cover 132>128 px: guard edge tiles
            out[(size_t)img * (128 * 128) + gy * 128 + gx] = fmaxf(accc, 0.f);
    }
}

extern "C" void kernel_launch(void* const* d_in, const int* in_sizes, int n_in,
                              void* d_out, int out_size, void* d_ws, size_t ws_size,
                              hipStream_t stream) {
    const float* x  = (const float*)d_in[0];
    const float* w1 = (const float*)d_in[1];
    const float* w2 = (const float*)d_in[2];
    const float* w3 = (const float*)d_in[3];
    unsigned int* wp = (unsigned int*)d_ws;
    float* out = (float*)d_out;
    pack_weights<<<dim3((WP_N + 255) / 256), dim3(256), 0, stream>>>(w1, w2, w3, wp);
    ds_fused<<<dim3(NWG), dim3(256), 0, stream>>>(x, wp, out);
}